// Round 6
// baseline (127.408 us; speedup 1.0000x reference)
//
#include <hip/hip_runtime.h>
#include <math.h>

// Problem constants
#define NN   768
#define HH   300
#define HP   320            // padded hidden dim (multiple of 64)
#define KD   768

// ---- ws float layout ----
// P2: [2 g][4 ks][768 i][320 h] gemm partials  @ 0   (g=0: hx, g=1: hy[perm])
// ES  esum[768] (float atomic accumulators)    @ 1966080
// CT  rowctr[16], grpctr (ints)                @ 1966848
// DS  t0sum, lsesum (doubles)                  @ 1966880
#define P_OFF    0
#define PKS_STR  245760           // 768*320
#define PG_STR   983040           // 4*PKS_STR
#define ES_OFF   1966080
#define CT_OFF   1966848
#define DS_OFF   1966880

// ========== K1: both GEMMs, transposed-to-[i][h] out, K-split 4 =============
// (byte-identical compute to round 4; block (0,0,0) also zeroes the atomic
// accumulator region, visible to k2f at the dispatch boundary)
__global__ __launch_bounds__(256) void k1_gemm(
    const float* __restrict__ x, const float* __restrict__ y,
    const int* __restrict__ perm, const float* __restrict__ W1,
    float* __restrict__ wsf)
{
    const int tid = threadIdx.x;
    if (blockIdx.x == 0 && blockIdx.y == 0 && blockIdx.z == 0) {
        for (int z = tid; z < 864; z += 256) wsf[ES_OFF + z] = 0.f;
    }
    const int tx = tid & 15;          // i: {4tx..} u {64+4tx..}
    const int ty = tid >> 4;          // h: 4ty..4ty+3
    const int i0 = blockIdx.x * 128;
    const int h0 = blockIdx.y * 64;
    const int g  = blockIdx.z & 1;
    const int ks = blockIdx.z >> 1;   // 0..3
    const int kbeg = ks * 192;

    const float* src = g ? y : x;
    const int koff = g ? KD : 0;

    __shared__ float Xt[32][132];     // Xt[k][i]
    __shared__ float Wt[32][68];      // Wt[k][h]

    float acc[4][8];
    #pragma unroll
    for (int r = 0; r < 4; ++r)
        #pragma unroll
        for (int cc = 0; cc < 8; ++cc) acc[r][cc] = 0.f;

    const int kq = (tid & 7) << 2;
    const float* xp[4];
    int xr[4];
    #pragma unroll
    for (int it = 0; it < 4; ++it) {
        int row = ((tid + it*256) >> 3);          // 0..127
        int gr = i0 + row;
        if (g) gr = perm[gr];
        xp[it] = src + (size_t)gr * KD + kbeg + kq;
        xr[it] = row;
    }
    const float* wp[2];
    int wr[2]; bool wv[2];
    #pragma unroll
    for (int it = 0; it < 2; ++it) {
        int hrow = ((tid + it*256) >> 3);         // 0..63
        int hg = h0 + hrow;
        wv[it] = hg < HH;
        wp[it] = W1 + (size_t)(wv[it] ? hg : 0) * (2*KD) + koff + kbeg + kq;
        wr[it] = hrow;
    }

    for (int kb = 0; kb < 192; kb += 32) {
        float4 xv[4], wvv[2];
        #pragma unroll
        for (int it = 0; it < 4; ++it) xv[it] = *(const float4*)(xp[it] + kb);
        #pragma unroll
        for (int it = 0; it < 2; ++it) {
            wvv[it] = *(const float4*)(wp[it] + kb);
            if (!wv[it]) wvv[it] = make_float4(0,0,0,0);
        }
        if (kb) __syncthreads();
        #pragma unroll
        for (int it = 0; it < 4; ++it) {
            Xt[kq+0][xr[it]] = xv[it].x; Xt[kq+1][xr[it]] = xv[it].y;
            Xt[kq+2][xr[it]] = xv[it].z; Xt[kq+3][xr[it]] = xv[it].w;
        }
        #pragma unroll
        for (int it = 0; it < 2; ++it) {
            Wt[kq+0][wr[it]] = wvv[it].x; Wt[kq+1][wr[it]] = wvv[it].y;
            Wt[kq+2][wr[it]] = wvv[it].z; Wt[kq+3][wr[it]] = wvv[it].w;
        }
        __syncthreads();

        #pragma unroll 8
        for (int k = 0; k < 32; ++k) {
            float4 a   = *(const float4*)&Wt[k][4*ty];
            float4 b0  = *(const float4*)&Xt[k][4*tx];
            float4 b1v = *(const float4*)&Xt[k][64 + 4*tx];
            float ar[4] = {a.x, a.y, a.z, a.w};
            float br[8] = {b0.x, b0.y, b0.z, b0.w, b1v.x, b1v.y, b1v.z, b1v.w};
            #pragma unroll
            for (int r = 0; r < 4; ++r)
                #pragma unroll
                for (int cc = 0; cc < 8; ++cc)
                    acc[r][cc] = fmaf(ar[r], br[cc], acc[r][cc]);
        }
    }

    float* dst = wsf + P_OFF + (size_t)(g*4 + ks) * PKS_STR;
    #pragma unroll
    for (int cc = 0; cc < 8; ++cc) {
        int i = i0 + ((cc >> 2) ? 64 : 0) + 4*tx + (cc & 3);
        float4 v = make_float4(acc[0][cc], acc[1][cc], acc[2][cc], acc[3][cc]);
        *(float4*)(dst + (size_t)i * HP + h0 + 4*ty) = v;
    }
}

// ======== K2f: combine partials + pairwise relu-dot + full finish ==========
// tile 48i x 48j, grid (16 j, 16 i) = 256 blocks x 512 threads; h-split:
// waves 0-3 h[0,152), waves 4-7 h[152,304). Staging sums the 4 K-partials of
// P2 inline (+b1 on the A side) -- absorbs k1b. Pad h>=300: P2 rows are zero
// AND w2s pad is zero => contributes exactly 0.
// Finish (absorbs k3) via device-scope atomics only (XCD-coherent, m20):
//   - esum[i] += partial rowsum      (float atomicAdd, 16 adders/row)
//   - t0 diagonal -> double atomicAdd into t0sum
//   - per-row-group counter: 16th block log-reduces its 48 rows
//     (wave-parallel atomic reads) -> double atomicAdd into lsesum
//   - 16th group-finisher computes out[0].
__global__ __launch_bounds__(512) void k2_pair(
    float* __restrict__ wsf, const float* __restrict__ w2,
    const int* __restrict__ perm, const float* __restrict__ b1,
    const float* __restrict__ b2, float* __restrict__ out)
{
    const int tid  = threadIdx.x;
    const int half = tid >> 8;         // 0 or 1
    const int t2   = tid & 255;
    const int tx = t2 & 15;            // j: {tx, tx+16, tx+32}
    const int ty = t2 >> 4;            // i: {ty, ty+16, ty+32}
    const int j0 = blockIdx.x * 48;
    const int i0 = blockIdx.y * 48;

    const float* PC = wsf + P_OFF;            // g=0 partials (hx)
    const float* PA = wsf + P_OFF + PG_STR;   // g=1 partials (hy[perm])
    float* esF   = wsf + ES_OFF;
    int*   ctr   = (int*)(wsf + CT_OFF);      // [0..15] rowctr, [16] grpctr
    double* t0s  = (double*)(wsf + DS_OFF);
    double* lses = (double*)(wsf + DS_OFF) + 1;

    __shared__ __align__(16) float As[2][48][156];   // [half][i][h-local]
    __shared__ __align__(16) float Cs[2][48][156];   // [half][j][h-local]
    __shared__ __align__(16) float w2s[304];
    __shared__ int finflag;

    if (tid < 76) {
        float4 wv = make_float4(0.f,0.f,0.f,0.f);
        if (tid < 75) wv = *(const float4*)(w2 + 4*tid);
        *(float4*)&w2s[4*tid] = wv;
    }
    // stage: per half, 48 rows x 38 quads; sum 4 K-partials inline (+b1 for A)
    for (int e = t2; e < 48 * 38; e += 256) {
        int i = e / 38, q = e % 38;
        int Q = half * 38 + q;                // global h-quad 0..75
        size_t oa = (size_t)(i0 + i) * HP + 4*Q;
        float4 a0 = *(const float4*)(PA + oa);
        float4 a1 = *(const float4*)(PA + PKS_STR + oa);
        float4 a2 = *(const float4*)(PA + 2*(size_t)PKS_STR + oa);
        float4 a3 = *(const float4*)(PA + 3*(size_t)PKS_STR + oa);
        float4 av = make_float4(a0.x+a1.x+a2.x+a3.x, a0.y+a1.y+a2.y+a3.y,
                                a0.z+a1.z+a2.z+a3.z, a0.w+a1.w+a2.w+a3.w);
        if (Q < 75) {                          // b1 has exactly 75 full quads
            float4 bq = *(const float4*)(b1 + 4*Q);
            av.x += bq.x; av.y += bq.y; av.z += bq.z; av.w += bq.w;
        }
        size_t oc = (size_t)(j0 + i) * HP + 4*Q;
        float4 c0 = *(const float4*)(PC + oc);
        float4 c1 = *(const float4*)(PC + PKS_STR + oc);
        float4 c2 = *(const float4*)(PC + 2*(size_t)PKS_STR + oc);
        float4 c3 = *(const float4*)(PC + 3*(size_t)PKS_STR + oc);
        float4 cv = make_float4(c0.x+c1.x+c2.x+c3.x, c0.y+c1.y+c2.y+c3.y,
                                c0.z+c1.z+c2.z+c3.z, c0.w+c1.w+c2.w+c3.w);
        *(float4*)&As[half][i][4*q] = av;
        *(float4*)&Cs[half][i][4*q] = cv;
    }
    __syncthreads();

    float acc[3][3];
    #pragma unroll
    for (int r = 0; r < 3; ++r)
        #pragma unroll
        for (int c = 0; c < 3; ++c) acc[r][c] = 0.f;

    const int hbeg = half * 152;
    #pragma unroll 2
    for (int k = 0; k < 38; ++k) {
        float4 wq = *(const float4*)&w2s[hbeg + 4*k];
        float4 a0 = *(const float4*)&As[half][ty     ][4*k];
        float4 a1 = *(const float4*)&As[half][ty + 16][4*k];
        float4 a2 = *(const float4*)&As[half][ty + 32][4*k];
        float4 c0 = *(const float4*)&Cs[half][tx     ][4*k];
        float4 c1 = *(const float4*)&Cs[half][tx + 16][4*k];
        float4 c2 = *(const float4*)&Cs[half][tx + 32][4*k];
        const float* wp  = (const float*)&wq;
        const float* ap0 = (const float*)&a0;
        const float* ap1 = (const float*)&a1;
        const float* ap2 = (const float*)&a2;
        const float* cp0 = (const float*)&c0;
        const float* cp1 = (const float*)&c1;
        const float* cp2 = (const float*)&c2;
        #pragma unroll
        for (int hh = 0; hh < 4; ++hh) {
            float wh = wp[hh];
            float av0 = ap0[hh], av1 = ap1[hh], av2 = ap2[hh];
            float cv0 = cp0[hh], cv1 = cp1[hh], cv2 = cp2[hh];
            acc[0][0] = fmaf(fmaxf(av0 + cv0, 0.f), wh, acc[0][0]);
            acc[0][1] = fmaf(fmaxf(av0 + cv1, 0.f), wh, acc[0][1]);
            acc[0][2] = fmaf(fmaxf(av0 + cv2, 0.f), wh, acc[0][2]);
            acc[1][0] = fmaf(fmaxf(av1 + cv0, 0.f), wh, acc[1][0]);
            acc[1][1] = fmaf(fmaxf(av1 + cv1, 0.f), wh, acc[1][1]);
            acc[1][2] = fmaf(fmaxf(av1 + cv2, 0.f), wh, acc[1][2]);
            acc[2][0] = fmaf(fmaxf(av2 + cv0, 0.f), wh, acc[2][0]);
            acc[2][1] = fmaf(fmaxf(av2 + cv1, 0.f), wh, acc[2][1]);
            acc[2][2] = fmaf(fmaxf(av2 + cv2, 0.f), wh, acc[2][2]);
        }
    }

    // combine halves through LDS (reuse As[0] region; all reads done)
    __syncthreads();
    float* comb = &As[0][0][0];        // [256][9]
    if (half) {
        float* cp = comb + t2 * 9;
        #pragma unroll
        for (int r = 0; r < 3; ++r)
            #pragma unroll
            for (int c = 0; c < 3; ++c) cp[r*3 + c] = acc[r][c];
    }
    __syncthreads();

    if (half == 0) {
        const float* cp = comb + t2 * 9;
        const float b2v = b2[0];
        #pragma unroll
        for (int r = 0; r < 3; ++r) {
            int i = i0 + ty + 16 * r;
            int pj = perm[i];
            float rsum = 0.f;
            #pragma unroll
            for (int c = 0; c < 3; ++c) {
                int j = j0 + tx + 16 * c;
                float u = acc[r][c] + cp[r*3 + c] + b2v;
                rsum += expf(u);
                if (j == pj) {         // exactly one thread chip-wide per row
                    float sp = (u > 0.f) ? u + log1pf(expf(-u)) : log1pf(expf(u));
                    atomicAdd(t0s, (double)sp);
                }
            }
            #pragma unroll
            for (int off = 8; off; off >>= 1)
                rsum += __shfl_xor(rsum, off, 16);
            if (tx == 0) atomicAdd(&esF[i], rsum);
        }
    }

    // -------- last-block-per-row-group: log-reduce 48 rows ----------------
    __syncthreads();
    if (tid == 0) {
        __threadfence();               // esum/t0 adds visible before counter
        int old = atomicAdd(&ctr[blockIdx.y], 1);
        finflag = (old == 15);
    }
    __syncthreads();
    if (finflag && tid < 64) {
        __threadfence();
        double lp = 0.0;
        if (tid < 48) {
            float e = atomicAdd(&esF[i0 + tid], 0.0f);   // coherent read
            lp = log((double)NN + (double)e);
        }
        #pragma unroll
        for (int off = 32; off; off >>= 1)
            lp += __shfl_down(lp, off);
        if (tid == 0) {
            atomicAdd(lses, lp);
            __threadfence();
            int o2 = atomicAdd(&ctr[16], 1);
            if (o2 == 15) {            // all 16 groups finished
                __threadfence();
                double t0v = atomicAdd(t0s, 0.0);
                double lsv = atomicAdd(lses, 0.0);
                double lb = t0v / (double)NN
                          - (lsv / (double)NN - log((double)NN));
                out[0] = (float)lb;
            }
        }
    }
}

extern "C" void kernel_launch(void* const* d_in, const int* in_sizes, int n_in,
                              void* d_out, int out_size, void* d_ws, size_t ws_size,
                              hipStream_t stream) {
    const float* x    = (const float*)d_in[0];
    const float* y    = (const float*)d_in[1];
    const int*   perm = (const int*)  d_in[2];
    const float* W1   = (const float*)d_in[3];
    const float* b1   = (const float*)d_in[4];
    const float* W2   = (const float*)d_in[5];
    const float* b2   = (const float*)d_in[6];
    float* wsf = (float*)d_ws;
    float* out = (float*)d_out;

    k1_gemm <<<dim3(6,5,8),  256, 0, stream>>>(x, y, perm, W1, wsf);
    k2_pair <<<dim3(16,16),  512, 0, stream>>>(wsf, W2, perm, b1, b2, out);
}

// Round 7
// 112.956 us; speedup vs baseline: 1.1280x; 1.1280x over previous
//
#include <hip/hip_runtime.h>
#include <math.h>

// Problem constants
#define NN   768
#define HH   300
#define HP   320            // padded hidden dim (multiple of 64)
#define KD   768

// ---- ws float layout (h-matrices stored [i][h], 320 h per row) ----
// P2: [2 g][8 ks][768 i][320 h] gemm partials  @ 0
// CF2 [768][320] = hx  (i-major)               @ 3932160
// AF2 [768][320] = hy[perm]+b1 (i-major)       @ 4177920
// RS  [16 jb][768] per-jblock exp-rowsums      @ 4423680
// T0  t0 contributions[768]                    @ 4435968
#define P_OFF    0
#define PKS_STR  245760           // 768*320
#define PG_STR   1966080          // 8*PKS_STR
#define CF_OFF   3932160
#define AF_OFF   4177920
#define RS_OFF   4423680
#define T0_OFF   4435968

// ========== K1: both GEMMs, [i][h] out, K-split 8, 8x8 register block =======
// P2[g][ks][i][h] = sum_{k in slice} W1[h][koff+k] * src[row(i)][k]
// tile 64h x 256i, 256 threads, per-thread 8h x 8i (64 accs), Kc=96.
// grid (3 i, 5 h, 16 = ks*2+g) = 240 blocks (~1/CU).
// Per k-step/thread: 4 ds_read_b128 feed 64 FMAs (was 3 feeding 32) ->
// CU LDS pipe 192 cyc/k vs 144*? : new bound 192 cyc/k * 96k = 7.7us
// (was 144*2 blocksteps.. measured 11.5us). All four reads conflict-free:
// h-quads {4ty, 32+4ty}, i-quads {4tx, 128+4tx} are contiguous per wave.
__global__ __launch_bounds__(256, 1) void k1_gemm(
    const float* __restrict__ x, const float* __restrict__ y,
    const int* __restrict__ perm, const float* __restrict__ W1,
    float* __restrict__ wsf)
{
    const int tid = threadIdx.x;
    const int tx = tid & 31;          // i: {4tx..4tx+3} u {128+4tx..}
    const int ty = tid >> 5;          // h: {4ty..4ty+3} u {32+4ty..}
    const int i0 = blockIdx.x * 256;
    const int h0 = blockIdx.y * 64;
    const int g  = blockIdx.z & 1;
    const int ks = blockIdx.z >> 1;   // 0..7
    const int kbeg = ks * 96;

    const float* src = g ? y : x;
    const int koff = g ? KD : 0;

    __shared__ float Xt[32][260];     // Xt[k][i]
    __shared__ float Wt[32][68];      // Wt[k][h]

    float acc[8][8];                  // [h r][i c]
    #pragma unroll
    for (int r = 0; r < 8; ++r)
        #pragma unroll
        for (int c = 0; c < 8; ++c) acc[r][c] = 0.f;

    const int kq = (tid & 7) << 2;
    const float* xp[8];
    int xr[8];
    #pragma unroll
    for (int it = 0; it < 8; ++it) {
        int row = ((tid + it*256) >> 3);          // 0..255
        int gr = i0 + row;
        if (g) gr = perm[gr];
        xp[it] = src + (size_t)gr * KD + kbeg + kq;
        xr[it] = row;
    }
    const float* wp[2];
    int wr[2]; bool wv[2];
    #pragma unroll
    for (int it = 0; it < 2; ++it) {
        int hrow = ((tid + it*256) >> 3);         // 0..63
        int hg = h0 + hrow;
        wv[it] = hg < HH;
        wp[it] = W1 + (size_t)(wv[it] ? hg : 0) * (2*KD) + koff + kbeg + kq;
        wr[it] = hrow;
    }

    for (int kb = 0; kb < 96; kb += 32) {
        float4 xv[8], wvv[2];
        #pragma unroll
        for (int it = 0; it < 8; ++it) xv[it] = *(const float4*)(xp[it] + kb);
        #pragma unroll
        for (int it = 0; it < 2; ++it) {
            wvv[it] = *(const float4*)(wp[it] + kb);
            if (!wv[it]) wvv[it] = make_float4(0,0,0,0);
        }
        if (kb) __syncthreads();
        #pragma unroll
        for (int it = 0; it < 8; ++it) {
            Xt[kq+0][xr[it]] = xv[it].x; Xt[kq+1][xr[it]] = xv[it].y;
            Xt[kq+2][xr[it]] = xv[it].z; Xt[kq+3][xr[it]] = xv[it].w;
        }
        #pragma unroll
        for (int it = 0; it < 2; ++it) {
            Wt[kq+0][wr[it]] = wvv[it].x; Wt[kq+1][wr[it]] = wvv[it].y;
            Wt[kq+2][wr[it]] = wvv[it].z; Wt[kq+3][wr[it]] = wvv[it].w;
        }
        __syncthreads();

        #pragma unroll 4
        for (int k = 0; k < 32; ++k) {
            float4 wlo = *(const float4*)&Wt[k][4*ty];
            float4 whi = *(const float4*)&Wt[k][32 + 4*ty];
            float4 xlo = *(const float4*)&Xt[k][4*tx];
            float4 xhi = *(const float4*)&Xt[k][128 + 4*tx];
            float hr[8] = {wlo.x, wlo.y, wlo.z, wlo.w,
                           whi.x, whi.y, whi.z, whi.w};
            float ir[8] = {xlo.x, xlo.y, xlo.z, xlo.w,
                           xhi.x, xhi.y, xhi.z, xhi.w};
            #pragma unroll
            for (int r = 0; r < 8; ++r)
                #pragma unroll
                for (int c = 0; c < 8; ++c)
                    acc[r][c] = fmaf(hr[r], ir[c], acc[r][c]);
        }
    }

    float* dst = wsf + P_OFF + (size_t)(g*8 + ks) * PKS_STR;
    #pragma unroll
    for (int c = 0; c < 8; ++c) {
        int i = i0 + ((c >> 2) ? 128 : 0) + 4*tx + (c & 3);
        float* rp = dst + (size_t)i * HP + h0;
        *(float4*)(rp + 4*ty) =
            make_float4(acc[0][c], acc[1][c], acc[2][c], acc[3][c]);
        *(float4*)(rp + 32 + 4*ty) =
            make_float4(acc[4][c], acc[5][c], acc[6][c], acc[7][c]);
    }
}

// ===== K1b: sum 8 K-partials -> CF2/AF2 ([i][h]); A += b1 ===================
// Pad rows h>=300 are zero in P2 (k1's wv guard) -> stay zero here.
__global__ __launch_bounds__(256) void k1b_combine(
    const float* __restrict__ b1, float* __restrict__ wsf)
{
    int idx = blockIdx.x * 256 + threadIdx.x;   // 480 blocks -> 122880
    int g = idx >= 61440;
    int rem = idx - g * 61440;
    int i = rem / 80;                 // 0..767
    int h4 = (rem % 80) * 4;          // 0..316

    float4 o = make_float4(0.f,0.f,0.f,0.f);
    const float* p = wsf + P_OFF + (size_t)g * PG_STR + (size_t)i * HP + h4;
    #pragma unroll
    for (int ks = 0; ks < 8; ++ks) {
        float4 v = *(const float4*)(p + (size_t)ks * PKS_STR);
        o.x += v.x; o.y += v.y; o.z += v.z; o.w += v.w;
    }
    if (g && h4 < HH) {               // HH divisible by 4 -> whole quad valid
        float4 bv = *(const float4*)(b1 + h4);
        o.x += bv.x; o.y += bv.y; o.z += bv.z; o.w += bv.w;
    }
    float* dst = wsf + (g ? AF_OFF : CF_OFF) + (size_t)i * HP + h4;
    *(float4*)dst = o;
}

// ======== K2: pairwise relu-dot, fused exp+rowsum, 512-thr h-split ==========
// (byte-identical to round 4 -- best passing variant)
__global__ __launch_bounds__(512, 2) void k2_pair(
    const float* __restrict__ wsf, const float* __restrict__ w2,
    const int* __restrict__ perm, const float* __restrict__ b2,
    float* __restrict__ rsO, float* __restrict__ t0c)
{
    const int tid  = threadIdx.x;
    const int half = tid >> 8;         // 0 or 1
    const int t2   = tid & 255;
    const int tx = t2 & 15;            // j: {tx, tx+16, tx+32}
    const int ty = t2 >> 4;            // i: {ty, ty+16, ty+32}
    const int j0 = blockIdx.x * 48;
    const int i0 = blockIdx.y * 48;
    const int hbeg = half * 152;       // 38 quads each; half1 top quad = pad

    const float* AF = wsf + AF_OFF;
    const float* CF = wsf + CF_OFF;

    __shared__ __align__(16) float As[2][48][156];   // [half][i][h-local]
    __shared__ __align__(16) float Cs[2][48][156];   // [half][j][h-local]
    __shared__ __align__(16) float w2s[304];

    if (tid < 76) {
        float4 wv = make_float4(0.f,0.f,0.f,0.f);
        if (tid < 75) wv = *(const float4*)(w2 + 4*tid);
        *(float4*)&w2s[4*tid] = wv;
    }
    // stage (each half stages its own 48 x 38-quad panels, coalesced rows)
    for (int e = t2; e < 48 * 38; e += 256) {
        int i = e / 38, q = e % 38;
        *(float4*)&As[half][i][4*q] =
            *(const float4*)(AF + (size_t)(i0 + i) * HP + hbeg + 4*q);
        *(float4*)&Cs[half][i][4*q] =
            *(const float4*)(CF + (size_t)(j0 + i) * HP + hbeg + 4*q);
    }
    __syncthreads();

    float acc[3][3];
    #pragma unroll
    for (int r = 0; r < 3; ++r)
        #pragma unroll
        for (int c = 0; c < 3; ++c) acc[r][c] = 0.f;

    #pragma unroll 2
    for (int k = 0; k < 38; ++k) {
        float4 wq = *(const float4*)&w2s[hbeg + 4*k];
        float4 a0 = *(const float4*)&As[half][ty     ][4*k];
        float4 a1 = *(const float4*)&As[half][ty + 16][4*k];
        float4 a2 = *(const float4*)&As[half][ty + 32][4*k];
        float4 c0 = *(const float4*)&Cs[half][tx     ][4*k];
        float4 c1 = *(const float4*)&Cs[half][tx + 16][4*k];
        float4 c2 = *(const float4*)&Cs[half][tx + 32][4*k];
        const float* wp  = (const float*)&wq;
        const float* ap0 = (const float*)&a0;
        const float* ap1 = (const float*)&a1;
        const float* ap2 = (const float*)&a2;
        const float* cp0 = (const float*)&c0;
        const float* cp1 = (const float*)&c1;
        const float* cp2 = (const float*)&c2;
        #pragma unroll
        for (int hh = 0; hh < 4; ++hh) {
            float wh = wp[hh];
            float av0 = ap0[hh], av1 = ap1[hh], av2 = ap2[hh];
            float cv0 = cp0[hh], cv1 = cp1[hh], cv2 = cp2[hh];
            acc[0][0] = fmaf(fmaxf(av0 + cv0, 0.f), wh, acc[0][0]);
            acc[0][1] = fmaf(fmaxf(av0 + cv1, 0.f), wh, acc[0][1]);
            acc[0][2] = fmaf(fmaxf(av0 + cv2, 0.f), wh, acc[0][2]);
            acc[1][0] = fmaf(fmaxf(av1 + cv0, 0.f), wh, acc[1][0]);
            acc[1][1] = fmaf(fmaxf(av1 + cv1, 0.f), wh, acc[1][1]);
            acc[1][2] = fmaf(fmaxf(av1 + cv2, 0.f), wh, acc[1][2]);
            acc[2][0] = fmaf(fmaxf(av2 + cv0, 0.f), wh, acc[2][0]);
            acc[2][1] = fmaf(fmaxf(av2 + cv1, 0.f), wh, acc[2][1]);
            acc[2][2] = fmaf(fmaxf(av2 + cv2, 0.f), wh, acc[2][2]);
        }
    }

    // combine halves through LDS (reuse As[0] region; all reads done)
    __syncthreads();
    float* comb = &As[0][0][0];        // [256][9]
    if (half) {
        float* cp = comb + t2 * 9;
        #pragma unroll
        for (int r = 0; r < 3; ++r)
            #pragma unroll
            for (int c = 0; c < 3; ++c) cp[r*3 + c] = acc[r][c];
    }
    __syncthreads();

    if (half == 0) {
        const float* cp = comb + t2 * 9;
        const float b2v = b2[0];
        #pragma unroll
        for (int r = 0; r < 3; ++r) {
            int i = i0 + ty + 16 * r;
            int pj = perm[i];
            float rsum = 0.f;
            #pragma unroll
            for (int c = 0; c < 3; ++c) {
                int j = j0 + tx + 16 * c;
                float u = acc[r][c] + cp[r*3 + c] + b2v;
                rsum += expf(u);
                if (j == pj)           // exactly one thread chip-wide per row
                    t0c[i] = (u > 0.f) ? u + log1pf(expf(-u)) : log1pf(expf(u));
            }
            #pragma unroll
            for (int off = 8; off; off >>= 1)
                rsum += __shfl_xor(rsum, off, 16);
            if (tx == 0) rsO[(size_t)blockIdx.x * NN + i] = rsum;
        }
    }
}

// ================= K3: combine RS partials + final f64 reduction ============
__global__ __launch_bounds__(256) void k3_final(
    const float* __restrict__ wsf, float* __restrict__ out)
{
    const int tid = threadIdx.x;
    const float* rs = wsf + RS_OFF;
    const float* t0 = wsf + T0_OFF;

    double st0 = 0.0, slse = 0.0;
    for (int i = tid; i < NN; i += 256) {
        float s = 0.f;
        #pragma unroll
        for (int jb = 0; jb < 16; ++jb) s += rs[(size_t)jb * NN + i];
        st0  += (double)t0[i];
        slse += log((double)NN + (double)s);
    }
    __shared__ double sa[256], sb[256];
    sa[tid] = st0; sb[tid] = slse;
    __syncthreads();
    for (int s = 128; s > 0; s >>= 1) {
        if (tid < s) { sa[tid] += sa[tid+s]; sb[tid] += sb[tid+s]; }
        __syncthreads();
    }
    if (tid == 0) {
        double lb = sa[0]/(double)NN - (sb[0]/(double)NN - log((double)NN));
        out[0] = (float)lb;
    }
}

extern "C" void kernel_launch(void* const* d_in, const int* in_sizes, int n_in,
                              void* d_out, int out_size, void* d_ws, size_t ws_size,
                              hipStream_t stream) {
    const float* x    = (const float*)d_in[0];
    const float* y    = (const float*)d_in[1];
    const int*   perm = (const int*)  d_in[2];
    const float* W1   = (const float*)d_in[3];
    const float* b1   = (const float*)d_in[4];
    const float* W2   = (const float*)d_in[5];
    const float* b2   = (const float*)d_in[6];
    float* wsf = (float*)d_ws;
    float* out = (float*)d_out;

    k1_gemm    <<<dim3(3,5,16), 256, 0, stream>>>(x, y, perm, W1, wsf);
    k1b_combine<<<480,          256, 0, stream>>>(b1, wsf);
    k2_pair    <<<dim3(16,16),  512, 0, stream>>>(wsf, W2, perm, b2,
                                                  wsf + RS_OFF, wsf + T0_OFF);
    k3_final   <<<1,            256, 0, stream>>>(wsf, out);
}